// Round 3
// baseline (8481.023 us; speedup 1.0000x reference)
//
#include <hip/hip_runtime.h>
#include <hip/hip_bf16.h>
#include <math.h>

typedef __hip_bfloat16 bf16;
typedef short bf16x8 __attribute__((ext_vector_type(8)));   // 8 bf16 = 4 VGPRs
typedef float f32x4 __attribute__((ext_vector_type(4)));

__device__ __forceinline__ float sigf(float x) { return 1.f / (1.f + expf(-x)); }

template<typename T> __device__ __forceinline__ T cvt_out(float v);
template<> __device__ __forceinline__ float cvt_out<float>(float v) { return v; }
template<> __device__ __forceinline__ bf16  cvt_out<bf16>(float v)  { return __float2bfloat16(v); }

__device__ __forceinline__ unsigned short f2bu(float x) {
  bf16 b = __float2bfloat16(x);
  return *reinterpret_cast<unsigned short*>(&b);
}

// async global->LDS, 16B per lane. LDS dest must be wave-uniform base + lane*16.
__device__ __forceinline__ void load_lds16(const void* g, void* l) {
  __builtin_amdgcn_global_load_lds(
      (const __attribute__((address_space(1))) unsigned int*)g,
      (__attribute__((address_space(3))) unsigned int*)l,
      16, 0, 0);
}

// ---------------- patch extraction: X[512,3,32,32] -> v_fw[64,512,48] f32 ----------------
__global__ void patch_kernel(const float* __restrict__ X, float* __restrict__ v) {
  int idx = blockIdx.x * 256 + threadIdx.x;
  int k = idx % 48;
  int b = (idx / 48) % 512;
  int t = idx / (48 * 512);
  int c = k >> 4, r = (k >> 2) & 3, s = k & 3;
  int ph = t & 7, pw = t >> 3;
  v[idx] = X[((b * 3 + c) * 32 + ph * 4 + r) * 32 + pw * 4 + s];
}

// ---------------- fp32 -> bf16 convert (x4 vectorized) ----------------
__global__ __launch_bounds__(256) void cvt_f32_bf16_k(const float* __restrict__ in,
                                                      bf16* __restrict__ out, size_t n4) {
  size_t i = (size_t)blockIdx.x * 256 + threadIdx.x;
  if (i >= n4) return;
  float4 v = ((const float4*)in)[i];
  ushort4 o;
  o.x = f2bu(v.x); o.y = f2bu(v.y); o.z = f2bu(v.z); o.w = f2bu(v.w);
  ((ushort4*)out)[i] = o;
}

// ---------------- legacy fp32 GEMM (only for xg1/xg2, K=48): C = A@W^T + b1 + b2 ----------------
template<typename OutT, bool RELU>
__global__ __launch_bounds__(256) void gemm_nt(
    const float* __restrict__ A, const float* __restrict__ W,
    const float* __restrict__ b1, const float* __restrict__ b2,
    OutT* __restrict__ C, int M, int N, int K, int ldc) {
  __shared__ float As[16][68];
  __shared__ float Ws[16][68];
  int tid = threadIdx.x;
  int tx = tid & 15, ty = tid >> 4;
  int m0 = blockIdx.y << 6, n0 = blockIdx.x << 6;
  const float* Ap = A + (size_t)m0 * K;
  const float* Wp = W + (size_t)n0 * K;
  float acc[4][4] = {};
  for (int k0 = 0; k0 < K; k0 += 16) {
#pragma unroll
    for (int i = 0; i < 4; i++) {
      int idx = tid + (i << 8);
      int row = idx >> 4, col = idx & 15;
      As[col][row] = Ap[(size_t)row * K + k0 + col];
      Ws[col][row] = Wp[(size_t)row * K + k0 + col];
    }
    __syncthreads();
#pragma unroll
    for (int kk = 0; kk < 16; kk++) {
      float4 av = *(const float4*)&As[kk][ty << 2];
      float4 wv = *(const float4*)&Ws[kk][tx << 2];
      float a[4] = {av.x, av.y, av.z, av.w};
      float w[4] = {wv.x, wv.y, wv.z, wv.w};
#pragma unroll
      for (int i = 0; i < 4; i++)
#pragma unroll
        for (int j = 0; j < 4; j++) acc[i][j] += a[i] * w[j];
    }
    __syncthreads();
  }
#pragma unroll
  for (int i = 0; i < 4; i++) {
    int m = m0 + (ty << 2) + i;
#pragma unroll
    for (int j = 0; j < 4; j++) {
      int n = n0 + (tx << 2) + j;
      float v = acc[i][j];
      if (b1) v += b1[n];
      if (b2) v += b2[n];
      if (RELU) v = fmaxf(v, 0.f);
      C[(size_t)m * ldc + n] = cvt_out<OutT>(v);
    }
  }
}

// ---------------- bf16 MFMA GEMM (NT): C[M,N] = A[M,K] @ W[N,K]^T (+bias) ----------------
template<typename OutT, bool RELU, bool SPLITK>
__global__ __launch_bounds__(256) void gemm_mfma(
    const bf16* __restrict__ A, const bf16* __restrict__ W,
    const float* __restrict__ b1, const float* __restrict__ b2,
    OutT* __restrict__ C, int M, int N, int K, int ldc, int ksplit) {
  __shared__ __align__(16) short As[128 * 32];
  __shared__ __align__(16) short Ws[128 * 32];
  int tid = threadIdx.x;
  int m0 = blockIdx.y << 7, n0 = blockIdx.x << 7;
  int kb = SPLITK ? blockIdx.z * ksplit : 0;
  int ke = SPLITK ? kb + ksplit : K;
  int w = tid >> 6, lane = tid & 63;
  int wm = (w >> 1) << 6, wn = (w & 1) << 6;
  int lm = lane & 15, quad = lane >> 4;
  f32x4 acc[4][4];
  f32x4 z4 = {0.f, 0.f, 0.f, 0.f};
#pragma unroll
  for (int i = 0; i < 4; i++)
#pragma unroll
    for (int j = 0; j < 4; j++) acc[i][j] = z4;

  int srow = tid >> 2;
  int soff = (tid & 3) * 8;
  const bf16* Ab  = A + (size_t)(m0 + srow) * K + kb + soff;
  const bf16* Ab2 = Ab + (size_t)64 * K;
  const bf16* Wb  = W + (size_t)(n0 + srow) * K + kb + soff;
  const bf16* Wb2 = Wb + (size_t)64 * K;
  short* AL  = &As[(size_t)tid * 8];
  short* AL2 = &As[(size_t)(tid + 256) * 8];
  short* WL  = &Ws[(size_t)tid * 8];
  short* WL2 = &Ws[(size_t)(tid + 256) * 8];

  for (int k0 = kb; k0 < ke; k0 += 32) {
    load_lds16(Ab, AL);  load_lds16(Ab2, AL2);
    load_lds16(Wb, WL);  load_lds16(Wb2, WL2);
    Ab += 32; Ab2 += 32; Wb += 32; Wb2 += 32;
    __syncthreads();
    bf16x8 af[4], wf[4];
#pragma unroll
    for (int i = 0; i < 4; i++) af[i] = *(const bf16x8*)&As[(wm + i * 16 + lm) * 32 + quad * 8];
#pragma unroll
    for (int j = 0; j < 4; j++) wf[j] = *(const bf16x8*)&Ws[(wn + j * 16 + lm) * 32 + quad * 8];
#pragma unroll
    for (int i = 0; i < 4; i++)
#pragma unroll
      for (int j = 0; j < 4; j++)
        acc[i][j] = __builtin_amdgcn_mfma_f32_16x16x32_bf16(af[i], wf[j], acc[i][j], 0, 0, 0);
    __syncthreads();
  }

  if (SPLITK) {
    float* P = (float*)C + (size_t)blockIdx.z * M * N;
#pragma unroll
    for (int i = 0; i < 4; i++)
#pragma unroll
      for (int j = 0; j < 4; j++) {
        int col = n0 + wn + j * 16 + lm;
        int rowb = m0 + wm + i * 16 + quad * 4;
#pragma unroll
        for (int r = 0; r < 4; r++)
          P[(size_t)(rowb + r) * N + col] = acc[i][j][r];
      }
  } else {
#pragma unroll
    for (int i = 0; i < 4; i++)
#pragma unroll
      for (int j = 0; j < 4; j++) {
        int col = n0 + wn + j * 16 + lm;
        int rowb = m0 + wm + i * 16 + quad * 4;
        float bias = (b1 ? b1[col] : 0.f) + (b2 ? b2[col] : 0.f);
#pragma unroll
        for (int r = 0; r < 4; r++) {
          float v = acc[i][j][r] + bias;
          if (RELU) v = fmaxf(v, 0.f);
          C[(size_t)(rowb + r) * ldc + col] = cvt_out<OutT>(v);
        }
      }
  }
}

// ---------------- split-K reduce + bias + relu ----------------
__global__ __launch_bounds__(256) void splitk_reduce(const float* __restrict__ P,
                                                     const float* __restrict__ bias,
                                                     float* __restrict__ out,
                                                     int MN, int N, int ldc, int nz) {
  int i = blockIdx.x * 256 + threadIdx.x;
  if (i >= MN) return;
  int m = i / N, n = i - m * N;
  float s = bias[n];
  for (int z = 0; z < nz; z++) s += P[(size_t)z * MN + i];
  out[(size_t)m * ldc + n] = fmaxf(s, 0.f);
}

// ================= persistent LSTM scan: 2 LSTMs x 64 steps, one launch =================
// grid (10 j-tiles, 8 r-tiles, 2 lstm) = 160 blocks, 256 threads, 1 block/CU (120 KB LDS).
// Whh slice resident in LDS for all 64 steps; c-state in registers; h (bf16 hi+lo,
// ping-pong in global) is the only cross-block state, synced by a device-scope barrier.
__global__ __launch_bounds__(256) void lstm_scan_persist(
    const bf16* __restrict__ xgA_, const bf16* __restrict__ xgB_,
    const bf16* __restrict__ WhhA, const bf16* __restrict__ WhhB,
    bf16* hAhi0, bf16* hAlo0, bf16* hAhi1, bf16* hAlo1,
    bf16* hBhi0, bf16* hBlo0, bf16* hBhi1, bf16* hBlo1,
    bf16* __restrict__ outb, long long tstride, int ldo,
    unsigned* bar_cnt, unsigned* bar_gen) {
  constexpr unsigned TOTAL = 160;
  __shared__ __align__(16) char smem[122880];
  short* WsS = (short*)smem;                 // 128 x 320 bf16 = 80 KB (chunk-swizzled)
  short* AhS = (short*)(smem + 81920);       // 5 x [64x32] staged h_hi chunks (20 KB)
  short* AlS = (short*)(smem + 102400);      // 5 x [64x32] staged h_lo chunks (20 KB)
  float* G   = (float*)(smem + 81920);       // 64 x 129 f32 preacts (33 KB, aliases stage)

  const int tid = threadIdx.x;
  const int jt = blockIdx.x, rt = blockIdx.y, lst = blockIdx.z;
  const int j0 = jt << 5, r0 = rt << 6;
  const bf16* Whh = lst ? WhhB : WhhA;
  const bf16* xg0 = lst ? xgB_ : xgA_;
  bf16* hhi[2] = { lst ? hBhi0 : hAhi0, lst ? hBhi1 : hAhi1 };
  bf16* hlo[2] = { lst ? hBlo0 : hAlo0, lst ? hBlo1 : hAlo1 };

  // ---- preload Whh slice (rows n = gate*32+jj -> 0..127, k 0..319) ----
  // 16B-chunk swizzle: physical chunk pc holds global chunk pc ^ (row&7)
  // (row stride 640B would otherwise 16-way-conflict the B-frag ds_read_b128).
  for (int i = 0; i < 20; i++) {
    int idx = i * 256 + tid;                 // 0..5119 chunks
    int row = idx / 40, pc = idx - row * 40;
    int gk = pc ^ (row & 7);
    int grow = ((row >> 5) * 320) + j0 + (row & 31);
    load_lds16(Whh + (size_t)grow * 320 + gk * 8, (char*)WsS + (size_t)idx * 16);
  }
  __syncthreads();

  const int g = tid >> 6, lane = tid & 63;   // wave g = gate
  const int lm = lane & 15, quad = lane >> 4;
  const int srow = tid >> 2, skoff = (tid & 3) * 8;
  const int rl = tid >> 2, jb = (tid & 3) * 8;
  const int r = r0 + rl;

  float cs[8];
#pragma unroll
  for (int q = 0; q < 8; q++) cs[q] = 0.f;

  for (int t = 0; t < 64; t++) {
    const bf16* xg = xg0 + (size_t)(lst ? 63 - t : t) * 655360;
    int par = t & 1;
    const bf16* hi_in = hhi[par];
    const bf16* lo_in = hlo[par];
    bf16* hi_out = hhi[par ^ 1];
    bf16* lo_out = hlo[par ^ 1];

    f32x4 acc[4][2];
    f32x4 z4 = {0.f, 0.f, 0.f, 0.f};
#pragma unroll
    for (int i = 0; i < 4; i++) { acc[i][0] = z4; acc[i][1] = z4; }

    if (t > 0) {
      const bf16* hb = hi_in + (size_t)(r0 + srow) * 320 + skoff;
      const bf16* lb = lo_in + (size_t)(r0 + srow) * 320 + skoff;
#pragma unroll
      for (int half = 0; half < 2; half++) {
#pragma unroll
        for (int ci = 0; ci < 5; ci++) {
          load_lds16(hb + half * 160 + ci * 32, (char*)AhS + ci * 4096 + (size_t)tid * 16);
          load_lds16(lb + half * 160 + ci * 32, (char*)AlS + ci * 4096 + (size_t)tid * 16);
        }
        __syncthreads();
#pragma unroll
        for (int ci = 0; ci < 5; ci++) {
          bf16x8 ah[4], al[4], bv[2];
          const short* Ab = AhS + ci * 2048;
          const short* Al2 = AlS + ci * 2048;
#pragma unroll
          for (int i = 0; i < 4; i++) {
            ah[i] = *(const bf16x8*)&Ab[(i * 16 + lm) * 32 + quad * 8];
            al[i] = *(const bf16x8*)&Al2[(i * 16 + lm) * 32 + quad * 8];
          }
          int kc8 = half * 20 + ci * 4 + quad;
#pragma unroll
          for (int j = 0; j < 2; j++) {
            int nrow = g * 32 + j * 16 + lm;
            bv[j] = *(const bf16x8*)&WsS[nrow * 320 + ((kc8 ^ (nrow & 7)) << 3)];
          }
#pragma unroll
          for (int i = 0; i < 4; i++)
#pragma unroll
            for (int j = 0; j < 2; j++) {
              acc[i][j] = __builtin_amdgcn_mfma_f32_16x16x32_bf16(ah[i], bv[j], acc[i][j], 0, 0, 0);
              acc[i][j] = __builtin_amdgcn_mfma_f32_16x16x32_bf16(al[i], bv[j], acc[i][j], 0, 0, 0);
            }
        }
        __syncthreads();
      }
    }

    // scatter gate preacts (C-layout) to G[row][gate*32+col]
#pragma unroll
    for (int i = 0; i < 4; i++)
#pragma unroll
      for (int j = 0; j < 2; j++)
#pragma unroll
        for (int rr = 0; rr < 4; rr++)
          G[(i * 16 + quad * 4 + rr) * 129 + g * 32 + j * 16 + lm] = acc[i][j][rr];
    __syncthreads();

    // pointwise: thread -> (row rl, 8 consecutive hidden cols), c-state in regs
    union { bf16x8 v; bf16 b[8]; } xv0, xv1, xv2, xv3, hv, lv;
    xv0.v = *(const bf16x8*)&xg[(size_t)r * 1280 + 0 * 320 + j0 + jb];
    xv1.v = *(const bf16x8*)&xg[(size_t)r * 1280 + 1 * 320 + j0 + jb];
    xv2.v = *(const bf16x8*)&xg[(size_t)r * 1280 + 2 * 320 + j0 + jb];
    xv3.v = *(const bf16x8*)&xg[(size_t)r * 1280 + 3 * 320 + j0 + jb];
#pragma unroll
    for (int q = 0; q < 8; q++) {
      float p0 = G[rl * 129 + 0 * 32 + jb + q] + __bfloat162float(xv0.b[q]);
      float p1 = G[rl * 129 + 1 * 32 + jb + q] + __bfloat162float(xv1.b[q]);
      float p2 = G[rl * 129 + 2 * 32 + jb + q] + __bfloat162float(xv2.b[q]);
      float p3 = G[rl * 129 + 3 * 32 + jb + q] + __bfloat162float(xv3.b[q]);
      float iv = sigf(p0), fv = sigf(p1), gv = tanhf(p2), ov = sigf(p3);
      float cn = fv * cs[q] + iv * gv;
      cs[q] = cn;
      float hn = ov * tanhf(cn);
      hv.b[q] = __float2bfloat16(hn);
      lv.b[q] = __float2bfloat16(hn - __bfloat162float(hv.b[q]));
    }
    size_t hoff = (size_t)r * 320 + j0 + jb;
    *(bf16x8*)(hi_out + hoff) = hv.v;
    *(bf16x8*)(lo_out + hoff) = lv.v;
    *(bf16x8*)(outb + (size_t)t * tstride + (size_t)r * ldo + lst * 320 + j0 + jb) = hv.v;

    // ---- device-scope grid barrier (sense via generation counter) ----
    if (t < 63) {
      __threadfence();          // release h writes device-wide
      __syncthreads();
      if (tid == 0) {
        unsigned g0 = __hip_atomic_load(bar_gen, __ATOMIC_RELAXED, __HIP_MEMORY_SCOPE_AGENT);
        unsigned old = __hip_atomic_fetch_add(bar_cnt, 1u, __ATOMIC_ACQ_REL, __HIP_MEMORY_SCOPE_AGENT);
        if (old == TOTAL - 1u) {
          __hip_atomic_store(bar_cnt, 0u, __ATOMIC_RELAXED, __HIP_MEMORY_SCOPE_AGENT);
          __hip_atomic_fetch_add(bar_gen, 1u, __ATOMIC_ACQ_REL, __HIP_MEMORY_SCOPE_AGENT);
        } else {
          while (__hip_atomic_load(bar_gen, __ATOMIC_RELAXED, __HIP_MEMORY_SCOPE_AGENT) == g0)
            __builtin_amdgcn_s_sleep(1);
        }
      }
      __syncthreads();
      __threadfence();          // acquire: invalidate stale cached h before next read
    }
  }
}

// ---------------- conv1 (3x3) + relu + maxpool2 fused ----------------
__global__ __launch_bounds__(256) void conv1_pool(
    const float* __restrict__ X, const float* __restrict__ w,
    const float* __restrict__ bias, float* __restrict__ pool) {
  int b = blockIdx.x;
  __shared__ float Xs[3 * 32 * 32];
  __shared__ float Wl[128 * 27];
  __shared__ float Bl[128];
  int tid = threadIdx.x;
  for (int i = tid; i < 3072; i += 256) Xs[i] = X[(size_t)b * 3072 + i];
  for (int i = tid; i < 3456; i += 256) Wl[i] = w[i];
  if (tid < 128) Bl[tid] = bias[tid];
  __syncthreads();
  int oc = tid & 127, half = tid >> 7;
  float wr[27];
#pragma unroll
  for (int q = 0; q < 27; q++) wr[q] = Wl[oc * 27 + q];
  float bv = Bl[oc];
  for (int p = half; p < 225; p += 2) {
    int i = p / 15, j = p % 15;
    float mx = -3.4e38f;
#pragma unroll
    for (int dy = 0; dy < 2; dy++)
#pragma unroll
      for (int dx = 0; dx < 2; dx++) {
        float s = bv;
        int rb = 2 * i + dy, cb = 2 * j + dx;
#pragma unroll
        for (int cc = 0; cc < 3; cc++)
#pragma unroll
          for (int kr = 0; kr < 3; kr++)
#pragma unroll
            for (int kc = 0; kc < 3; kc++)
              s += wr[cc * 9 + kr * 3 + kc] * Xs[cc * 1024 + (rb + kr) * 32 + cb + kc];
        mx = fmaxf(mx, s);
      }
    pool[((size_t)(b * 128 + oc)) * 225 + p] = fmaxf(mx, 0.f);
  }
}

// ---------------- batchnorm stats -> fold to a*x+s ----------------
__global__ void bn_stats(const float* __restrict__ x, int C, int per, int B,
                         const float* __restrict__ g, const float* __restrict__ bb,
                         float* __restrict__ a, float* __restrict__ s) {
  int c = blockIdx.x;
  int n = B * per;
  float sum = 0.f, sq = 0.f;
  for (int i = threadIdx.x; i < n; i += 256) {
    int b = i / per, p = i - b * per;
    float v = x[((size_t)b * C + c) * per + p];
    sum += v; sq += v * v;
  }
  __shared__ float S1[256], S2[256];
  S1[threadIdx.x] = sum; S2[threadIdx.x] = sq;
  __syncthreads();
  for (int off = 128; off > 0; off >>= 1) {
    if (threadIdx.x < off) { S1[threadIdx.x] += S1[threadIdx.x + off]; S2[threadIdx.x] += S2[threadIdx.x + off]; }
    __syncthreads();
  }
  if (threadIdx.x == 0) {
    float m = S1[0] / n;
    float var = S2[0] / n - m * m;
    float av = g[c] * rsqrtf(var + 1e-5f);
    a[c] = av; s[c] = bb[c] - m * av;
  }
}

__global__ void bn_apply_bf16(const float* __restrict__ x, bf16* __restrict__ y,
                              const float* __restrict__ a, const float* __restrict__ s,
                              int per, int C, size_t total) {
  size_t i = (size_t)blockIdx.x * 256 + threadIdx.x;
  if (i < total) {
    int ch = (int)((i / per) % C);
    y[i] = __float2bfloat16(a[ch] * x[i] + s[ch]);
  }
}

// ---------------- conv2 (4x4, 128->48), bn1 on load, relu on store ----------------
__global__ __launch_bounds__(192) void conv2_kernel(
    const float* __restrict__ pool, const float* __restrict__ w,
    const float* __restrict__ bias, const float* __restrict__ a1,
    const float* __restrict__ s1, float* __restrict__ out) {
  int rg = blockIdx.x, b = blockIdx.y;
  int r0 = rg * 4;
  __shared__ float L[128 * 7 * 15];
  int tid = threadIdx.x;
#pragma unroll
  for (int i = 0; i < 70; i++) {
    int idx = tid + i * 192;
    int c = idx / 105, rem = idx % 105;
    int r = rem / 15, col = rem % 15;
    L[idx] = pool[((size_t)(b * 128 + c)) * 225 + (r0 + r) * 15 + col] * a1[c] + s1[c];
  }
  __syncthreads();
  int oc = tid % 48, orow = tid / 48;
  float acc[12];
  float bv = bias[oc];
#pragma unroll
  for (int j = 0; j < 12; j++) acc[j] = bv;
  for (int c = 0; c < 128; c++) {
#pragma unroll
    for (int kr = 0; kr < 4; kr++) {
      float v[15];
#pragma unroll
      for (int q = 0; q < 15; q++) v[q] = L[(c * 7 + orow + kr) * 15 + q];
      const float* wp = &w[((size_t)(oc * 128 + c)) * 16 + kr * 4];
#pragma unroll
      for (int kc = 0; kc < 4; kc++) {
        float wv = wp[kc];
#pragma unroll
        for (int j = 0; j < 12; j++) acc[j] += wv * v[j + kc];
      }
    }
  }
  float* op = &out[((size_t)(b * 48 + oc)) * 144 + (r0 + orow) * 12];
#pragma unroll
  for (int j = 0; j < 12; j++) op[j] = fmaxf(acc[j], 0.f);
}

// ---------------- fc + log_softmax ----------------
__global__ __launch_bounds__(64) void fc_logsoftmax(
    const float* __restrict__ A, const float* __restrict__ W,
    const float* __restrict__ bias, float* __restrict__ out) {
  int b = blockIdx.x, lane = threadIdx.x;
  float acc[10] = {};
  for (int k = lane; k < 4096; k += 64) {
    float x = A[(size_t)b * 4096 + k];
#pragma unroll
    for (int o = 0; o < 10; o++) acc[o] += x * W[o * 4096 + k];
  }
#pragma unroll
  for (int o = 0; o < 10; o++)
    for (int off = 32; off > 0; off >>= 1) acc[o] += __shfl_down(acc[o], off);
  if (lane == 0) {
    float l[10];
    float m = -3.4e38f;
#pragma unroll
    for (int o = 0; o < 10; o++) { l[o] = acc[o] + bias[o]; m = fmaxf(m, l[o]); }
    float se = 0.f;
#pragma unroll
    for (int o = 0; o < 10; o++) se += expf(l[o] - m);
    float ls = logf(se);
#pragma unroll
    for (int o = 0; o < 10; o++) out[b * 10 + o] = l[o] - m - ls;
  }
}

__global__ void zero_k(float* __restrict__ p, size_t n) {
  size_t i = (size_t)blockIdx.x * 256 + threadIdx.x;
  if (i < n) p[i] = 0.f;
}

extern "C" void kernel_launch(void* const* d_in, const int* in_sizes, int n_in,
                              void* d_out, int out_size, void* d_ws, size_t ws_size,
                              hipStream_t stream) {
  const float* X    = (const float*)d_in[0];
  const float* c1w  = (const float*)d_in[1];
  const float* c1b  = (const float*)d_in[2];
  const float* bn1g = (const float*)d_in[3];
  const float* bn1b = (const float*)d_in[4];
  const float* c2w  = (const float*)d_in[5];
  const float* c2b  = (const float*)d_in[6];
  const float* bn2g = (const float*)d_in[7];
  const float* bn2b = (const float*)d_in[8];
  const float *Wih[4], *Whh[4], *bih[4], *bhh[4];
  for (int i = 0; i < 4; i++) {
    Wih[i] = (const float*)d_in[9 + 4 * i];
    Whh[i] = (const float*)d_in[10 + 4 * i];
    bih[i] = (const float*)d_in[11 + 4 * i];
    bhh[i] = (const float*)d_in[12 + 4 * i];
  }
  const float* d1w = (const float*)d_in[25];
  const float* d1b = (const float*)d_in[26];
  const float* d2w = (const float*)d_in[27];
  const float* d2b = (const float*)d_in[28];
  const float* fcw = (const float*)d_in[29];
  const float* fcb = (const float*)d_in[30];
  float* out = (float*)d_out;

  // ---- workspace layout ----
  char* p = (char*)d_ws;
  float* v_fw = (float*)p;  p += (size_t)64 * 512 * 48 * 4;         // 6.3 MB
  char* R = p;              p += (size_t)167772160;                  // xg region (2x 83.9MB)
  bf16* xgA = (bf16*)R;
  bf16* xgB = xgA + (size_t)41943040;
  bf16* h_fw = (bf16*)p;    p += (size_t)64 * 512 * 640 * 2;         // 41.9 MB
  bf16* hfm  = (bf16*)p;    p += (size_t)512 * 40960 * 2;            // 41.9 MB
  bf16* wih3b = (bf16*)p;   p += (size_t)1280 * 640 * 2;
  bf16* wih4b = (bf16*)p;   p += (size_t)1280 * 640 * 2;
  bf16* whhb[4];
  for (int i = 0; i < 4; i++) { whhb[i] = (bf16*)p; p += (size_t)1280 * 320 * 2; }
  bf16* hstates = (bf16*)p;  p += (size_t)8 * 163840 * 2;            // 2.6 MB (8 h buffers)
  float* P = (float*)p;      p += (size_t)4 * 512 * 2048 * 4;        // 16.8 MB split-K partials
  float* outcat = (float*)p; p += (size_t)512 * 4096 * 4;            // 8.4 MB
  float* bnp = (float*)p;    p += 2048;
  unsigned* bar = (unsigned*)p; p += 256;                            // barrier cnt/gen
  // conv aliases inside R (dead after dense1):
  float* pool   = (float*)R;                                         // 59.0 MB
  float* c2out  = (float*)(R + 58982400);                            // 14.2 MB
  bf16*  c2outb = (bf16*)(R + 58982400 + 14155776);                  // 7.1 MB
  bf16*  d2wb   = (bf16*)(R + 58982400 + 14155776 + 7077888);        // 28.3 MB
  bf16*  d1wb   = (bf16*)R;                                          // 167.8 MB (whole R)
  float* a1 = bnp, *s1 = bnp + 128, *a2 = bnp + 256, *s2 = bnp + 304;

  bf16* hA0h = hstates;
  bf16* hA0l = hstates + 163840;
  bf16* hA1h = hstates + 327680;
  bf16* hA1l = hstates + 491520;
  bf16* hB0h = hstates + 655360;
  bf16* hB0l = hstates + 819200;
  bf16* hB1h = hstates + 983040;
  bf16* hB1l = hstates + 1146880;

  // 1) patches + small weight conversions + barrier init
  patch_kernel<<<6144, 256, 0, stream>>>(X, v_fw);
  for (int i = 0; i < 4; i++)
    cvt_f32_bf16_k<<<400, 256, 0, stream>>>(Whh[i], whhb[i], 102400);
  cvt_f32_bf16_k<<<800, 256, 0, stream>>>(Wih[2], wih3b, 204800);
  cvt_f32_bf16_k<<<800, 256, 0, stream>>>(Wih[3], wih4b, 204800);
  zero_k<<<1, 64, 0, stream>>>((float*)bar, 64);

  // 2) input projections for LSTM 1/2 (K=48, fp32 gemm, bf16 out)
  gemm_nt<bf16, false><<<dim3(20, 512), 256, 0, stream>>>(v_fw, Wih[0], bih[0], bhh[0], xgA, 32768, 1280, 48, 1280);
  gemm_nt<bf16, false><<<dim3(20, 512), 256, 0, stream>>>(v_fw, Wih[1], bih[1], bhh[1], xgB, 32768, 1280, 48, 1280);

  // 3) phase A scan (persistent, 1 launch)
  lstm_scan_persist<<<dim3(10, 8, 2), 256, 0, stream>>>(xgA, xgB, whhb[0], whhb[1],
      hA0h, hA0l, hA1h, hA1l, hB0h, hB0l, hB1h, hB1l,
      h_fw, 327680LL, 640, bar, bar + 16);

  // 4) input projections for LSTM 3/4 (MFMA, overwrite xg region)
  gemm_mfma<bf16, false, false><<<dim3(10, 256, 1), 256, 0, stream>>>(h_fw, wih3b, bih[2], bhh[2], xgA, 32768, 1280, 640, 1280, 0);
  gemm_mfma<bf16, false, false><<<dim3(10, 256, 1), 256, 0, stream>>>(h_fw, wih4b, bih[3], bhh[3], xgB, 32768, 1280, 640, 1280, 0);

  // 5) phase B scan (persistent, 1 launch) -> hfm
  lstm_scan_persist<<<dim3(10, 8, 2), 256, 0, stream>>>(xgA, xgB, whhb[2], whhb[3],
      hA0h, hA0l, hA1h, hA1l, hB0h, hB0l, hB1h, hB1l,
      hfm, 640LL, 40960, bar, bar + 16);

  // 6) dense1 (split-K=4) -> outcat[:, 0:2048]
  cvt_f32_bf16_k<<<81920, 256, 0, stream>>>(d1w, d1wb, 20971520);
  gemm_mfma<float, false, true><<<dim3(16, 4, 4), 256, 0, stream>>>(hfm, d1wb, nullptr, nullptr, P, 512, 2048, 40960, 2048, 10240);
  splitk_reduce<<<4096, 256, 0, stream>>>(P, d1b, outcat, 1048576, 2048, 4096, 4);

  // 7) conv branch (d1wb dead -> pool/c2out alias R)
  conv1_pool<<<512, 256, 0, stream>>>(X, c1w, c1b, pool);
  bn_stats<<<128, 256, 0, stream>>>(pool, 128, 225, 512, bn1g, bn1b, a1, s1);
  conv2_kernel<<<dim3(3, 512), 192, 0, stream>>>(pool, c2w, c2b, a1, s1, c2out);
  bn_stats<<<48, 256, 0, stream>>>(c2out, 48, 144, 512, bn2g, bn2b, a2, s2);
  bn_apply_bf16<<<13824, 256, 0, stream>>>(c2out, c2outb, a2, s2, 144, 48, (size_t)3538944);

  // 8) dense2 (split-K=4) -> outcat[:, 2048:4096]
  cvt_f32_bf16_k<<<13824, 256, 0, stream>>>(d2w, d2wb, 3538944);
  gemm_mfma<float, false, true><<<dim3(16, 4, 4), 256, 0, stream>>>(c2outb, d2wb, nullptr, nullptr, P, 512, 2048, 6912, 2048, 1728);
  splitk_reduce<<<4096, 256, 0, stream>>>(P, d2b, outcat + 2048, 1048576, 2048, 4096, 4);

  // 9) fc + log_softmax
  fc_logsoftmax<<<512, 64, 0, stream>>>(outcat, fcw, fcb, out);
}